// Round 5
// baseline (240.999 us; speedup 1.0000x reference)
//
#include <hip/hip_runtime.h>
#include <hip/hip_bf16.h>

#define N_CTX 4096
#define NH    16
#define DH    64
#define DIM   1024   // NH * DH
#define NSPLIT 4
#define KT_PER_SPLIT (N_CTX / 64 / NSPLIT)   // 16

typedef __attribute__((ext_vector_type(8))) short bf16x8;  // 8 bf16 in 4 VGPRs
typedef __attribute__((ext_vector_type(4))) float f32x4;   // MFMA C/D
typedef __attribute__((ext_vector_type(2))) unsigned u32x2;

// RNE float->bf16 (non-hot paths)
__device__ __forceinline__ ushort f2bf(float f) {
    union { float f; unsigned u; } x; x.f = f;
    unsigned r = (x.u + 0x7FFFu + ((x.u >> 16) & 1u)) >> 16;
    return (ushort)r;
}
__device__ __forceinline__ float bf2f(ushort u) {
    union { unsigned u; float f; } x; x.u = ((unsigned)u) << 16; return x.f;
}
__device__ __forceinline__ unsigned fbits(float f) {
    union { float f; unsigned u; } x; x.f = f; return x.u;
}
// pack two floats to packed bf16 pair (round-half-up), 3 VALU ops
__device__ __forceinline__ unsigned pack_bf16(float lo, float hi) {
    unsigned a = fbits(lo) + 0x8000u;
    unsigned b = fbits(hi) + 0x8000u;
#if defined(__has_builtin)
#if __has_builtin(__builtin_amdgcn_perm)
    return __builtin_amdgcn_perm(b, a, 0x07060302u);
#else
    return (a >> 16) | (b & 0xFFFF0000u);
#endif
#else
    return (a >> 16) | (b & 0xFFFF0000u);
#endif
}
__device__ __forceinline__ float fast_exp2(float x) {
#if defined(__has_builtin)
#if __has_builtin(__builtin_amdgcn_exp2f)
    return __builtin_amdgcn_exp2f(x);
#else
    return exp2f(x);
#endif
#else
    return exp2f(x);
#endif
}
// hw sin/cos of x (radians): revolutions + v_fract + v_sin/v_cos.
__device__ __forceinline__ void fast_sincos(float ang, float* s, float* c) {
#if defined(__has_builtin)
#if __has_builtin(__builtin_amdgcn_sinf) && __has_builtin(__builtin_amdgcn_cosf) && __has_builtin(__builtin_amdgcn_fractf)
    float rev = __builtin_amdgcn_fractf(ang * 0.15915494309189535f);
    *s = __builtin_amdgcn_sinf(rev);
    *c = __builtin_amdgcn_cosf(rev);
    return;
#endif
#endif
    sincosf(ang, s, c);
}

// Cross-lane row swaps (gfx950 VALU ops, 2 outputs per instruction).
// pl32: a' = {a[0:31], b[0:31]}, b' = {a[32:63], b[32:63]}
__device__ __forceinline__ void pl32_swap(unsigned &a, unsigned &b) {
#if defined(__has_builtin)
#if __has_builtin(__builtin_amdgcn_permlane32_swap)
    u32x2 r = __builtin_amdgcn_permlane32_swap(a, b, false, false);
    a = r[0]; b = r[1];
    return;
#endif
#endif
    const int lane = (int)(threadIdx.x & 63);
    unsigned ax = (unsigned)__shfl_xor((int)a, 32, 64);
    unsigned bx = (unsigned)__shfl_xor((int)b, 32, 64);
    unsigned na = (lane & 32) ? bx : a;
    unsigned nb = (lane & 32) ? b  : ax;
    a = na; b = nb;
}
// pl16: a' = {a[0:15], b[0:15], a[32:47], b[32:47]},
//       b' = {a[16:31], b[16:31], a[48:63], b[48:63]}
__device__ __forceinline__ void pl16_swap(unsigned &a, unsigned &b) {
#if defined(__has_builtin)
#if __has_builtin(__builtin_amdgcn_permlane16_swap)
    u32x2 r = __builtin_amdgcn_permlane16_swap(a, b, false, false);
    a = r[0]; b = r[1];
    return;
#endif
#endif
    const int lane = (int)(threadIdx.x & 63);
    unsigned ax = (unsigned)__shfl_xor((int)a, 16, 64);
    unsigned bx = (unsigned)__shfl_xor((int)b, 16, 64);
    unsigned na = (lane & 16) ? bx : a;
    unsigned nb = (lane & 16) ? b  : ax;
    a = na; b = nb;
}

// 0.125 * log2(e): folded into Q during prep; softmax shift-invariance lets us
// drop the bias term entirely (p = exp2(s) directly, p <= 2^18.1).
#define SC 0.18033688011112042f
// log2(10000)/32
#define LF 0.4152410118609203f

// ---------------------------------------------------------------------------
// prep (fused q+k): x (N, DIM) fp32 -> rope -> l2norm -> * qk_scale * premul
//       -> xb bf16 [h][n][d].  blockIdx.y: 0 = q (premul SC), 1 = k.
// ---------------------------------------------------------------------------
__global__ __launch_bounds__(256) void prep_kernel(
    const float* __restrict__ qg, const float* __restrict__ kg,
    const float* __restrict__ qk_scale,
    ushort* __restrict__ qb, ushort* __restrict__ kb)
{
    const int lane = threadIdx.x & 63;
    const int wave = threadIdx.x >> 6;
    const int row  = blockIdx.x * 4 + wave;   // row = n*NH + h
    const int n = row >> 4;
    const int h = row & 15;
    const int isk = blockIdx.y;
    const float* __restrict__ x = isk ? kg : qg;
    ushort* __restrict__ xb = isk ? kb : qb;
    const float premul = isk ? 1.0f : SC;

    float val = x[(size_t)n * DIM + h * DH + lane];
    float other = __shfl_xor(val, 1, 64);

    const int i = lane >> 1;
    float inv_freq = fast_exp2((float)i * -LF);   // 10000^(-i/32)
    float ang = (float)n * inv_freq;
    float s, c;
    fast_sincos(ang, &s, &c);

    float r = (lane & 1) ? fmaf(other, s, val * c)
                         : fmaf(val, c, -(other * s));

    float ss = r * r;
    #pragma unroll
    for (int off = 32; off > 0; off >>= 1)
        ss += __shfl_xor(ss, off, 64);
    float invn = rsqrtf(fmaxf(ss, 1e-24f));
    float scl  = qk_scale[lane] * premul;

    xb[((size_t)h * N_CTX + n) * DH + lane] = f2bf(r * invn * scl);
}

// ---------------------------------------------------------------------------
// vtrans: v (N, DIM) fp32 -> vt bf16 [h][d][n]
// ---------------------------------------------------------------------------
__global__ __launch_bounds__(256) void vtrans_kernel(
    const float* __restrict__ v, ushort* __restrict__ vt)
{
    __shared__ ushort L[64][68];
    const int kt = blockIdx.x, h = blockIdx.y, t = threadIdx.x;

    for (int e = t; e < 4096; e += 256) {
        int key = e >> 6, d = e & 63;
        float f = v[(size_t)(kt * 64 + key) * DIM + h * DH + d];
        L[d][key] = f2bf(f);
    }
    __syncthreads();
    for (int e = t; e < 4096; e += 256) {
        int d = e >> 6, key = e & 63;
        vt[((size_t)h * DH + d) * N_CTX + kt * 64 + key] = L[d][key];
    }
}

// ---------------------------------------------------------------------------
// wconv: w_out (DIM, DIM) fp32 -> bf16 row-major
// ---------------------------------------------------------------------------
__global__ __launch_bounds__(256) void wconv_kernel(
    const float* __restrict__ w, ushort* __restrict__ wb)
{
    int i = (blockIdx.x * 256 + threadIdx.x) * 4;
    float4 f = *(const float4*)&w[i];
    ushort4 u;
    u.x = f2bf(f.x); u.y = f2bf(f.y); u.z = f2bf(f.z); u.w = f2bf(f.w);
    *(ushort4*)&wb[i] = u;
}

// ---------------------------------------------------------------------------
// attn: MFMA flash attention, P in registers, K=32 PV via permlane assembly.
// Double-buffered K/V LDS tiles -> ONE barrier per K-tile (was 2).
// Round-3 counters: 40% of cycles neither VALU nor MFMA issued (VALUBusy 58,
// MfmaUtil 28, occupancy ~2-3 blocks/CU) — barrier drains were the stall.
// Per iter: [issue next-tile global loads] -> compute buf[cur] ->
// [write buf[cur^1]] -> barrier.  Writes to cur^1 are safe while others read
// cur; single barrier publishes writes AND retires reads of cur.
// Barriers are in uniform control flow (loop bounds compile-time) — no
// divergent-barrier hang.  NOTE: no min-waves launch bound — (256,6) spills
// o_acc (round 1: 970 MB scratch writes).
// ---------------------------------------------------------------------------
__global__ __launch_bounds__(256) void attn_kernel(
    const ushort* __restrict__ qb, const ushort* __restrict__ kb,
    const ushort* __restrict__ vt, ushort* __restrict__ opart,
    float* __restrict__ lpart)
{
    __shared__ ushort Ks[2][64][72];    // [buf][key][d]
    __shared__ ushort Vt[2][64][72];    // [buf][d][key]

    const int h     = blockIdx.y;
    const int qbase = blockIdx.x * 128;
    const int sp    = blockIdx.z;
    const int kbase = sp * (N_CTX / NSPLIT);
    const int t    = threadIdx.x;
    const int w    = t >> 6;
    const int lane = t & 63;
    const int l15  = lane & 15;
    const int quad = lane >> 4;

    // Q B-fragments: 2 query-tiles x 2 k-halves (queries w*32 + qt*16 + l15)
    bf16x8 qf[2][2];
    #pragma unroll
    for (int qt = 0; qt < 2; qt++) {
        const size_t qrow = ((size_t)h * N_CTX + qbase + w * 32 + qt * 16 + l15) * DH;
        qf[qt][0] = *(const bf16x8*)&qb[qrow + quad * 8];
        qf[qt][1] = *(const bf16x8*)&qb[qrow + 32 + quad * 8];
    }

    float l_part[2] = {0.0f, 0.0f};
    f32x4 o_acc[4][2];
    #pragma unroll
    for (int dt = 0; dt < 4; dt++)
        #pragma unroll
        for (int qt = 0; qt < 2; qt++)
            o_acc[dt][qt] = (f32x4){0.f, 0.f, 0.f, 0.f};

    // staging: 256 threads, 2 x 16B chunks each of K and V (rows sr, sr+32)
    const int sr = t >> 3;
    const int sc = (t & 7) * 8;
    const ushort* kp0 = &kb[((size_t)h * N_CTX + kbase + sr) * DH + sc];
    const ushort* kp1 = kp0 + (size_t)32 * DH;
    const ushort* vp0 = &vt[((size_t)h * DH + sr) * N_CTX + kbase + sc];
    const ushort* vp1 = vp0 + (size_t)32 * N_CTX;

    // prologue: tile 0 -> LDS[0]
    bf16x8 kr0 = *(const bf16x8*)kp0, kr1 = *(const bf16x8*)kp1;
    bf16x8 vr0 = *(const bf16x8*)vp0, vr1 = *(const bf16x8*)vp1;
    kp0 += (size_t)64 * DH; kp1 += (size_t)64 * DH;
    vp0 += 64;              vp1 += 64;
    *(bf16x8*)&Ks[0][sr][sc]      = kr0;
    *(bf16x8*)&Ks[0][sr + 32][sc] = kr1;
    *(bf16x8*)&Vt[0][sr][sc]      = vr0;
    *(bf16x8*)&Vt[0][sr + 32][sc] = vr1;
    __syncthreads();

    for (int kt = 0; kt < KT_PER_SPLIT; kt++) {
        const int cur = kt & 1;
        const bool more = (kt + 1 < KT_PER_SPLIT);
        if (more) {                            // issue early; hides under compute
            kr0 = *(const bf16x8*)kp0;  kp0 += (size_t)64 * DH;
            kr1 = *(const bf16x8*)kp1;  kp1 += (size_t)64 * DH;
            vr0 = *(const bf16x8*)vp0;  vp0 += 64;
            vr1 = *(const bf16x8*)vp1;  vp1 += 64;
        }

        // ---- fused S+PV over 2 key-subtile PAIRS (32 keys each)
        #pragma unroll
        for (int jp = 0; jp < 2; jp++) {
            unsigned pa[2][2], pb[2][2];   // [qt][dword]: subtile jj=0 / jj=1
            #pragma unroll
            for (int jj = 0; jj < 2; jj++) {
                const int j = jp * 2 + jj;
                bf16x8 kf0 = *(const bf16x8*)&Ks[cur][j * 16 + l15][quad * 8];
                bf16x8 kf1 = *(const bf16x8*)&Ks[cur][j * 16 + l15][32 + quad * 8];
                f32x4 s0 = (f32x4){0.f, 0.f, 0.f, 0.f};
                f32x4 s1 = (f32x4){0.f, 0.f, 0.f, 0.f};
                s0 = __builtin_amdgcn_mfma_f32_16x16x32_bf16(kf0, qf[0][0], s0, 0, 0, 0);
                s1 = __builtin_amdgcn_mfma_f32_16x16x32_bf16(kf0, qf[1][0], s1, 0, 0, 0);
                s0 = __builtin_amdgcn_mfma_f32_16x16x32_bf16(kf1, qf[0][1], s0, 0, 0, 0);
                s1 = __builtin_amdgcn_mfma_f32_16x16x32_bf16(kf1, qf[1][1], s1, 0, 0, 0);

                {
                    float p0 = fast_exp2(s0.x), p1 = fast_exp2(s0.y);
                    float p2 = fast_exp2(s0.z), p3 = fast_exp2(s0.w);
                    l_part[0] += (p0 + p1) + (p2 + p3);
                    unsigned d0 = pack_bf16(p0, p1), d1 = pack_bf16(p2, p3);
                    if (jj == 0) { pa[0][0] = d0; pa[0][1] = d1; }
                    else         { pb[0][0] = d0; pb[0][1] = d1; }
                }
                {
                    float p0 = fast_exp2(s1.x), p1 = fast_exp2(s1.y);
                    float p2 = fast_exp2(s1.z), p3 = fast_exp2(s1.w);
                    l_part[1] += (p0 + p1) + (p2 + p3);
                    unsigned d0 = pack_bf16(p0, p1), d1 = pack_bf16(p2, p3);
                    if (jj == 0) { pa[1][0] = d0; pa[1][1] = d1; }
                    else         { pb[1][0] = d0; pb[1][1] = d1; }
                }
            }

            // assemble K=32 B-fragments in-register (4 permlane ops per qt)
            bf16x8 pw[2];
            #pragma unroll
            for (int qt = 0; qt < 2; qt++) {
                unsigned x0 = pa[qt][0], y0 = pb[qt][0];
                unsigned x1 = pa[qt][1], y1 = pb[qt][1];
                pl32_swap(x0, y0);
                pl32_swap(x1, y1);
                pl16_swap(x0, y0);   // x0 = W0 (k 8q+0,1), y0 = W2 (k 8q+4,5)
                pl16_swap(x1, y1);   // x1 = W1 (k 8q+2,3), y1 = W3 (k 8q+6,7)
                uint4 wd; wd.x = x0; wd.y = x1; wd.z = y0; wd.w = y1;
                pw[qt] = __builtin_bit_cast(bf16x8, wd);
            }

            // PV at K=32: vf is the A-operand (A[row=d=l15][k=quad*8+i]);
            // shared by both query-tiles.  O layout matches prior rounds.
            #pragma unroll
            for (int dt = 0; dt < 4; dt++) {
                bf16x8 vf = *(const bf16x8*)&Vt[cur][dt * 16 + l15][jp * 32 + quad * 8];
                o_acc[dt][0] = __builtin_amdgcn_mfma_f32_16x16x32_bf16(vf, pw[0], o_acc[dt][0], 0, 0, 0);
                o_acc[dt][1] = __builtin_amdgcn_mfma_f32_16x16x32_bf16(vf, pw[1], o_acc[dt][1], 0, 0, 0);
            }
        }

        if (more) {                            // publish next tile, single barrier
            *(bf16x8*)&Ks[cur ^ 1][sr][sc]      = kr0;
            *(bf16x8*)&Ks[cur ^ 1][sr + 32][sc] = kr1;
            *(bf16x8*)&Vt[cur ^ 1][sr][sc]      = vr0;
            *(bf16x8*)&Vt[cur ^ 1][sr + 32][sc] = vr1;
            __syncthreads();
        }
    }

    // l: reduce across quads (disjoint key subsets per quad)
    #pragma unroll
    for (int qt = 0; qt < 2; qt++) {
        float v = l_part[qt];
        v += __shfl_xor(v, 16, 64);
        v += __shfl_xor(v, 32, 64);
        if (quad == 0)
            lpart[(size_t)sp * NH * N_CTX + (size_t)h * N_CTX
                  + qbase + w * 32 + qt * 16 + l15] = v;
    }

    // O partial (pre-division), bf16 [sp][N][DIM]
    #pragma unroll
    for (int qt = 0; qt < 2; qt++)
        #pragma unroll
        for (int dt = 0; dt < 4; dt++) {
            f32x4 o = o_acc[dt][qt];
            ushort4 ov;
            ov.x = f2bf(o.x); ov.y = f2bf(o.y);
            ov.z = f2bf(o.z); ov.w = f2bf(o.w);
            *(ushort4*)&opart[((size_t)sp * N_CTX + qbase + w * 32 + qt * 16 + l15) * DIM
                              + h * DH + dt * 16 + quad * 4] = ov;
        }
}

// ---------------------------------------------------------------------------
// combine: attnb[n][c] = bf16( (sum_sp O_sp)[n][c] / (sum_sp l_sp)[n,h] )
// ---------------------------------------------------------------------------
__global__ __launch_bounds__(256) void combine_kernel(
    const ushort* __restrict__ opart, const float* __restrict__ lpart,
    ushort* __restrict__ attnb)
{
    const int idx = blockIdx.x * 256 + threadIdx.x;   // one per 4 elements
    const int n   = idx >> 8;
    const int rem = idx & 255;
    const int h   = rem >> 4;
    const size_t e = (size_t)n * DIM + h * DH + (rem & 15) * 4;

    float s0 = 0.f, s1 = 0.f, s2 = 0.f, s3 = 0.f, lsum = 0.f;
    #pragma unroll
    for (int sp = 0; sp < NSPLIT; sp++) {
        ushort4 u = *(const ushort4*)&opart[(size_t)sp * N_CTX * DIM + e];
        s0 += bf2f(u.x); s1 += bf2f(u.y); s2 += bf2f(u.z); s3 += bf2f(u.w);
        lsum += lpart[(size_t)sp * NH * N_CTX + (size_t)h * N_CTX + n];
    }
    float li = 1.0f / lsum;

    ushort4 r;
    r.x = f2bf(s0 * li); r.y = f2bf(s1 * li);
    r.z = f2bf(s2 * li); r.w = f2bf(s3 * li);
    *(ushort4*)&attnb[e] = r;
}

// ---------------------------------------------------------------------------
// proj (MFMA): out[n][o] = sum_c A[n][c] * W[o][c] + b[o]
// 64x64 block tile, grid (64,16) = 1024 blocks = 4/CU.
// Same double-buffer/single-barrier restructure as attn.
// ---------------------------------------------------------------------------
__global__ __launch_bounds__(256) void proj_kernel(
    const ushort* __restrict__ A, const ushort* __restrict__ W,
    const float* __restrict__ bias, float* __restrict__ out)
{
    __shared__ ushort As[2][64][72];
    __shared__ ushort Ws[2][64][72];

    const int nbase = blockIdx.x * 64;
    const int obase = blockIdx.y * 64;
    const int t    = threadIdx.x;
    const int w    = t >> 6;
    const int lane = t & 63;
    const int l15  = lane & 15;
    const int quad = lane >> 4;
    const int rw   = (w >> 1) * 32;
    const int cw   = (w & 1) * 32;

    f32x4 acc[2][2];
    #pragma unroll
    for (int mt = 0; mt < 2; mt++)
        #pragma unroll
        for (int nt = 0; nt < 2; nt++)
            acc[mt][nt] = (f32x4){0.f, 0.f, 0.f, 0.f};

    // staging: rows sr, sr+32 of the 64-row K-slab, 16B per chunk
    const int sr = t >> 3;
    const int sc = (t & 7) * 8;
    const ushort* ap0 = &A[(size_t)(nbase + sr) * DIM + sc];
    const ushort* ap1 = ap0 + (size_t)32 * DIM;
    const ushort* wp0 = &W[(size_t)(obase + sr) * DIM + sc];
    const ushort* wp1 = wp0 + (size_t)32 * DIM;

    bf16x8 ar0 = *(const bf16x8*)ap0, ar1 = *(const bf16x8*)ap1;
    bf16x8 wr0 = *(const bf16x8*)wp0, wr1 = *(const bf16x8*)wp1;
    ap0 += 64; ap1 += 64; wp0 += 64; wp1 += 64;
    *(bf16x8*)&As[0][sr][sc]      = ar0;
    *(bf16x8*)&As[0][sr + 32][sc] = ar1;
    *(bf16x8*)&Ws[0][sr][sc]      = wr0;
    *(bf16x8*)&Ws[0][sr + 32][sc] = wr1;
    __syncthreads();

    for (int kt = 0; kt < DIM / 64; kt++) {
        const int cur = kt & 1;
        const bool more = (kt + 1 < DIM / 64);
        if (more) {
            ar0 = *(const bf16x8*)ap0;  ap0 += 64;
            ar1 = *(const bf16x8*)ap1;  ap1 += 64;
            wr0 = *(const bf16x8*)wp0;  wp0 += 64;
            wr1 = *(const bf16x8*)wp1;  wp1 += 64;
        }

        bf16x8 af[2][2], bfr[2][2];
        #pragma unroll
        for (int mt = 0; mt < 2; mt++)
            #pragma unroll
            for (int kh = 0; kh < 2; kh++)
                af[mt][kh] = *(const bf16x8*)&As[cur][rw + mt * 16 + l15][kh * 32 + quad * 8];
        #pragma unroll
        for (int nt = 0; nt < 2; nt++)
            #pragma unroll
            for (int kh = 0; kh < 2; kh++)
                bfr[nt][kh] = *(const bf16x8*)&Ws[cur][cw + nt * 16 + l15][kh * 32 + quad * 8];

        #pragma unroll
        for (int mt = 0; mt < 2; mt++)
            #pragma unroll
            for (int nt = 0; nt < 2; nt++) {
                acc[mt][nt] = __builtin_amdgcn_mfma_f32_16x16x32_bf16(af[mt][0], bfr[nt][0], acc[mt][nt], 0, 0, 0);
                acc[mt][nt] = __builtin_amdgcn_mfma_f32_16x16x32_bf16(af[mt][1], bfr[nt][1], acc[mt][nt], 0, 0, 0);
            }

        if (more) {
            *(bf16x8*)&As[cur ^ 1][sr][sc]      = ar0;
            *(bf16x8*)&As[cur ^ 1][sr + 32][sc] = ar1;
            *(bf16x8*)&Ws[cur ^ 1][sr][sc]      = wr0;
            *(bf16x8*)&Ws[cur ^ 1][sr + 32][sc] = wr1;
            __syncthreads();
        }
    }

    #pragma unroll
    for (int nt = 0; nt < 2; nt++) {
        int o = obase + cw + nt * 16 + l15;
        float bb = bias[o];
        #pragma unroll
        for (int mt = 0; mt < 2; mt++) {
            int nrow = nbase + rw + mt * 16 + quad * 4;
            out[(size_t)(nrow + 0) * DIM + o] = acc[mt][nt].x + bb;
            out[(size_t)(nrow + 1) * DIM + o] = acc[mt][nt].y + bb;
            out[(size_t)(nrow + 2) * DIM + o] = acc[mt][nt].z + bb;
            out[(size_t)(nrow + 3) * DIM + o] = acc[mt][nt].w + bb;
        }
    }
}

// ---------------------------------------------------------------------------
extern "C" void kernel_launch(void* const* d_in, const int* in_sizes, int n_in,
                              void* d_out, int out_size, void* d_ws, size_t ws_size,
                              hipStream_t stream)
{
    const float* q        = (const float*)d_in[0];
    const float* k        = (const float*)d_in[1];
    const float* v        = (const float*)d_in[2];
    const float* qk_scale = (const float*)d_in[3];
    const float* w_out    = (const float*)d_in[4];
    const float* b_out    = (const float*)d_in[5];
    float* out = (float*)d_out;

    const size_t per = (size_t)NH * N_CTX * DH;      // 4.19M elements
    ushort* qb    = (ushort*)d_ws;
    ushort* kb    = qb + per;
    ushort* vtg   = kb + per;
    ushort* attnb = vtg + per;                       // (N, DIM) bf16
    ushort* wb    = attnb + per;                     // (DIM, DIM) bf16
    ushort* opart = wb + (size_t)DIM * DIM;          // NSPLIT x (N, DIM) bf16
    float*  lpart = (float*)(opart + (size_t)NSPLIT * N_CTX * DIM);

    prep_kernel<<<dim3(N_CTX * NH / 4, 2), 256, 0, stream>>>(q, k, qk_scale, qb, kb);
    vtrans_kernel<<<dim3(N_CTX / 64, NH), 256, 0, stream>>>(v, vtg);
    wconv_kernel<<<dim3(DIM * DIM / 1024), 256, 0, stream>>>(w_out, wb);
    attn_kernel<<<dim3(N_CTX / 128, NH, NSPLIT), 256, 0, stream>>>(qb, kb, vtg, opart, lpart);
    combine_kernel<<<dim3(N_CTX * DIM / 4 / 256), 256, 0, stream>>>(opart, lpart, attnb);
    proj_kernel<<<dim3(N_CTX / 64, DIM / 64), 256, 0, stream>>>(attnb, wb, b_out, out);
}

// Round 6
// 238.332 us; speedup vs baseline: 1.0112x; 1.0112x over previous
//
#include <hip/hip_runtime.h>
#include <hip/hip_bf16.h>

#define N_CTX 4096
#define NH    16
#define DH    64
#define DIM   1024   // NH * DH
#define NSPLIT 4
#define KT_PER_SPLIT (N_CTX / 64 / NSPLIT)   // 16

typedef __attribute__((ext_vector_type(8))) short bf16x8;  // 8 bf16 in 4 VGPRs
typedef __attribute__((ext_vector_type(4))) float f32x4;   // MFMA C/D
typedef __attribute__((ext_vector_type(2))) unsigned u32x2;

// RNE float->bf16 (non-hot paths)
__device__ __forceinline__ ushort f2bf(float f) {
    union { float f; unsigned u; } x; x.f = f;
    unsigned r = (x.u + 0x7FFFu + ((x.u >> 16) & 1u)) >> 16;
    return (ushort)r;
}
__device__ __forceinline__ float bf2f(ushort u) {
    union { unsigned u; float f; } x; x.u = ((unsigned)u) << 16; return x.f;
}
__device__ __forceinline__ unsigned fbits(float f) {
    union { float f; unsigned u; } x; x.f = f; return x.u;
}
// pack two floats to packed bf16 pair (round-half-up), 3 VALU ops
__device__ __forceinline__ unsigned pack_bf16(float lo, float hi) {
    unsigned a = fbits(lo) + 0x8000u;
    unsigned b = fbits(hi) + 0x8000u;
#if defined(__has_builtin)
#if __has_builtin(__builtin_amdgcn_perm)
    return __builtin_amdgcn_perm(b, a, 0x07060302u);
#else
    return (a >> 16) | (b & 0xFFFF0000u);
#endif
#else
    return (a >> 16) | (b & 0xFFFF0000u);
#endif
}
__device__ __forceinline__ float fast_exp2(float x) {
#if defined(__has_builtin)
#if __has_builtin(__builtin_amdgcn_exp2f)
    return __builtin_amdgcn_exp2f(x);
#else
    return exp2f(x);
#endif
#else
    return exp2f(x);
#endif
}
// hw sin/cos of x (radians): revolutions + v_fract + v_sin/v_cos.
__device__ __forceinline__ void fast_sincos(float ang, float* s, float* c) {
#if defined(__has_builtin)
#if __has_builtin(__builtin_amdgcn_sinf) && __has_builtin(__builtin_amdgcn_cosf) && __has_builtin(__builtin_amdgcn_fractf)
    float rev = __builtin_amdgcn_fractf(ang * 0.15915494309189535f);
    *s = __builtin_amdgcn_sinf(rev);
    *c = __builtin_amdgcn_cosf(rev);
    return;
#endif
#endif
    sincosf(ang, s, c);
}

// Cross-lane row swaps (gfx950 VALU ops, 2 outputs per instruction).
// pl32: a' = {a[0:31], b[0:31]}, b' = {a[32:63], b[32:63]}
__device__ __forceinline__ void pl32_swap(unsigned &a, unsigned &b) {
#if defined(__has_builtin)
#if __has_builtin(__builtin_amdgcn_permlane32_swap)
    u32x2 r = __builtin_amdgcn_permlane32_swap(a, b, false, false);
    a = r[0]; b = r[1];
    return;
#endif
#endif
    const int lane = (int)(threadIdx.x & 63);
    unsigned ax = (unsigned)__shfl_xor((int)a, 32, 64);
    unsigned bx = (unsigned)__shfl_xor((int)b, 32, 64);
    unsigned na = (lane & 32) ? bx : a;
    unsigned nb = (lane & 32) ? b  : ax;
    a = na; b = nb;
}
// pl16: a' = {a[0:15], b[0:15], a[32:47], b[32:47]},
//       b' = {a[16:31], b[16:31], a[48:63], b[48:63]}
__device__ __forceinline__ void pl16_swap(unsigned &a, unsigned &b) {
#if defined(__has_builtin)
#if __has_builtin(__builtin_amdgcn_permlane16_swap)
    u32x2 r = __builtin_amdgcn_permlane16_swap(a, b, false, false);
    a = r[0]; b = r[1];
    return;
#endif
#endif
    const int lane = (int)(threadIdx.x & 63);
    unsigned ax = (unsigned)__shfl_xor((int)a, 16, 64);
    unsigned bx = (unsigned)__shfl_xor((int)b, 16, 64);
    unsigned na = (lane & 16) ? bx : a;
    unsigned nb = (lane & 16) ? b  : ax;
    a = na; b = nb;
}

// 0.125 * log2(e): folded into Q during prep; softmax shift-invariance lets us
// drop the bias term entirely (p = exp2(s) directly, p <= 2^18.1).
#define SC 0.18033688011112042f
// log2(10000)/32
#define LF 0.4152410118609203f

// ---------------------------------------------------------------------------
// rope_table: cos/sin of n * 10000^(-i/32) for (n,i) in N_CTX x 32, f32.
// Computed ONCE — prep was recomputing each pair 32x (16 heads x {q,k}).
// ---------------------------------------------------------------------------
__global__ __launch_bounds__(256) void rope_table_kernel(
    float* __restrict__ ct, float* __restrict__ st)
{
    const int idx = blockIdx.x * 256 + threadIdx.x;   // n*32 + i
    const int n = idx >> 5, i = idx & 31;
    float inv_freq = fast_exp2((float)i * -LF);       // 10000^(-i/32)
    float s, c;
    fast_sincos((float)n * inv_freq, &s, &c);
    ct[idx] = c; st[idx] = s;
}

// ---------------------------------------------------------------------------
// prep (fused q+k): x (N, DIM) fp32 -> rope (table) -> l2norm -> * qk_scale *
//       premul -> xb bf16 [h][n][d].  blockIdx.y: 0 = q (premul SC), 1 = k.
// ---------------------------------------------------------------------------
__global__ __launch_bounds__(256) void prep_kernel(
    const float* __restrict__ qg, const float* __restrict__ kg,
    const float* __restrict__ qk_scale,
    const float* __restrict__ ct, const float* __restrict__ st,
    ushort* __restrict__ qb, ushort* __restrict__ kb)
{
    const int lane = threadIdx.x & 63;
    const int wave = threadIdx.x >> 6;
    const int row  = blockIdx.x * 4 + wave;   // row = n*NH + h
    const int n = row >> 4;
    const int h = row & 15;
    const int isk = blockIdx.y;
    const float* __restrict__ x = isk ? kg : qg;
    ushort* __restrict__ xb = isk ? kb : qb;
    const float premul = isk ? 1.0f : SC;

    float val = x[(size_t)n * DIM + h * DH + lane];
    float other = __shfl_xor(val, 1, 64);

    const int i = lane >> 1;
    const float c = ct[(n << 5) | i];
    const float s = st[(n << 5) | i];

    float r = (lane & 1) ? fmaf(other, s, val * c)
                         : fmaf(val, c, -(other * s));

    float ss = r * r;
    #pragma unroll
    for (int off = 32; off > 0; off >>= 1)
        ss += __shfl_xor(ss, off, 64);
    float invn = rsqrtf(fmaxf(ss, 1e-24f));
    float scl  = qk_scale[lane] * premul;

    xb[((size_t)h * N_CTX + n) * DH + lane] = f2bf(r * invn * scl);
}

// ---------------------------------------------------------------------------
// vtrans: v (N, DIM) fp32 -> vt bf16 [h][d][n]
// ---------------------------------------------------------------------------
__global__ __launch_bounds__(256) void vtrans_kernel(
    const float* __restrict__ v, ushort* __restrict__ vt)
{
    __shared__ ushort L[64][68];
    const int kt = blockIdx.x, h = blockIdx.y, t = threadIdx.x;

    for (int e = t; e < 4096; e += 256) {
        int key = e >> 6, d = e & 63;
        float f = v[(size_t)(kt * 64 + key) * DIM + h * DH + d];
        L[d][key] = f2bf(f);
    }
    __syncthreads();
    for (int e = t; e < 4096; e += 256) {
        int d = e >> 6, key = e & 63;
        vt[((size_t)h * DH + d) * N_CTX + kt * 64 + key] = L[d][key];
    }
}

// ---------------------------------------------------------------------------
// wconv: w_out (DIM, DIM) fp32 -> bf16 row-major
// ---------------------------------------------------------------------------
__global__ __launch_bounds__(256) void wconv_kernel(
    const float* __restrict__ w, ushort* __restrict__ wb)
{
    int i = (blockIdx.x * 256 + threadIdx.x) * 4;
    float4 f = *(const float4*)&w[i];
    ushort4 u;
    u.x = f2bf(f.x); u.y = f2bf(f.y); u.z = f2bf(f.z); u.w = f2bf(f.w);
    *(ushort4*)&wb[i] = u;
}

// ---------------------------------------------------------------------------
// attn: MFMA flash attention, P in registers, K=32 PV via permlane assembly.
// ROUND 6: 4 query-tiles per wave (64 queries/wave, 256/block).  K/V LDS
// fragment reads, staging, and barriers are shared across qt — their cost
// per unit work HALVES vs the 2-qt kernel (R0/R3/R5 all ~106-112 µs were
// pinned by this shared overhead, not by barriers or Ps traffic).
// Structure: R3's 2-barrier single-buffer (best measured, 18.4 KB LDS).
// NOTE: no min-waves launch bound — caps spill o_acc (round 1: 970 MB
// scratch writes).  WRITE_SIZE == 33.8 MB is the no-spill tripwire.
// ---------------------------------------------------------------------------
__global__ __launch_bounds__(256) void attn_kernel(
    const ushort* __restrict__ qb, const ushort* __restrict__ kb,
    const ushort* __restrict__ vt, ushort* __restrict__ opart,
    float* __restrict__ lpart)
{
    __shared__ ushort Ks[64][72];    // [key][d]
    __shared__ ushort Vt[64][72];    // [d][key]

    const int h     = blockIdx.y;
    const int qbase = blockIdx.x * 256;
    const int sp    = blockIdx.z;
    const int kbase = sp * (N_CTX / NSPLIT);
    const int t    = threadIdx.x;
    const int w    = t >> 6;
    const int lane = t & 63;
    const int l15  = lane & 15;
    const int quad = lane >> 4;

    // Q B-fragments: 4 query-tiles x 2 k-halves (queries w*64 + qt*16 + l15)
    bf16x8 qf[4][2];
    #pragma unroll
    for (int qt = 0; qt < 4; qt++) {
        const size_t qrow = ((size_t)h * N_CTX + qbase + w * 64 + qt * 16 + l15) * DH;
        qf[qt][0] = *(const bf16x8*)&qb[qrow + quad * 8];
        qf[qt][1] = *(const bf16x8*)&qb[qrow + 32 + quad * 8];
    }

    float l_part[4] = {0.f, 0.f, 0.f, 0.f};
    f32x4 o_acc[4][4];               // [dt][qt]
    #pragma unroll
    for (int dt = 0; dt < 4; dt++)
        #pragma unroll
        for (int qt = 0; qt < 4; qt++)
            o_acc[dt][qt] = (f32x4){0.f, 0.f, 0.f, 0.f};

    // staging: 256 threads, 2 x 16B chunks each of K and V (rows sr, sr+32)
    const int sr = t >> 3;
    const int sc = (t & 7) * 8;
    const ushort* kp0 = &kb[((size_t)h * N_CTX + kbase + sr) * DH + sc];
    const ushort* kp1 = kp0 + (size_t)32 * DH;
    const ushort* vp0 = &vt[((size_t)h * DH + sr) * N_CTX + kbase + sc];
    const ushort* vp1 = vp0 + (size_t)32 * N_CTX;
    bf16x8 kr0 = *(const bf16x8*)kp0, kr1 = *(const bf16x8*)kp1;
    bf16x8 vr0 = *(const bf16x8*)vp0, vr1 = *(const bf16x8*)vp1;

    for (int kt = 0; kt < KT_PER_SPLIT; kt++) {
        __syncthreads();                       // A: all waves done with prev tile
        *(bf16x8*)&Ks[sr][sc]      = kr0;
        *(bf16x8*)&Ks[sr + 32][sc] = kr1;
        *(bf16x8*)&Vt[sr][sc]      = vr0;
        *(bf16x8*)&Vt[sr + 32][sc] = vr1;
        __syncthreads();                       // B: staging visible
        if (kt + 1 < KT_PER_SPLIT) {           // prefetch next tile into regs
            kr0 = *(const bf16x8*)(kp0 + (size_t)(kt + 1) * 64 * DH);
            kr1 = *(const bf16x8*)(kp1 + (size_t)(kt + 1) * 64 * DH);
            vr0 = *(const bf16x8*)(vp0 + (size_t)(kt + 1) * 64);
            vr1 = *(const bf16x8*)(vp1 + (size_t)(kt + 1) * 64);
        }

        // ---- fused S+PV over 2 key-subtile PAIRS (32 keys each)
        #pragma unroll
        for (int jp = 0; jp < 2; jp++) {
            unsigned pa[4][2], pb[4][2];   // [qt][dword]: subtile jj=0 / jj=1
            #pragma unroll
            for (int jj = 0; jj < 2; jj++) {
                const int j = jp * 2 + jj;
                bf16x8 kf0 = *(const bf16x8*)&Ks[j * 16 + l15][quad * 8];
                bf16x8 kf1 = *(const bf16x8*)&Ks[j * 16 + l15][32 + quad * 8];
                f32x4 sv[4];
                #pragma unroll
                for (int qt = 0; qt < 4; qt++)
                    sv[qt] = (f32x4){0.f, 0.f, 0.f, 0.f};
                #pragma unroll
                for (int qt = 0; qt < 4; qt++)
                    sv[qt] = __builtin_amdgcn_mfma_f32_16x16x32_bf16(kf0, qf[qt][0], sv[qt], 0, 0, 0);
                #pragma unroll
                for (int qt = 0; qt < 4; qt++)
                    sv[qt] = __builtin_amdgcn_mfma_f32_16x16x32_bf16(kf1, qf[qt][1], sv[qt], 0, 0, 0);

                #pragma unroll
                for (int qt = 0; qt < 4; qt++) {
                    float p0 = fast_exp2(sv[qt].x), p1 = fast_exp2(sv[qt].y);
                    float p2 = fast_exp2(sv[qt].z), p3 = fast_exp2(sv[qt].w);
                    l_part[qt] += (p0 + p1) + (p2 + p3);
                    unsigned d0 = pack_bf16(p0, p1), d1 = pack_bf16(p2, p3);
                    if (jj == 0) { pa[qt][0] = d0; pa[qt][1] = d1; }
                    else         { pb[qt][0] = d0; pb[qt][1] = d1; }
                }
            }

            // assemble K=32 B-fragments in-register (4 permlane ops per qt)
            bf16x8 pw[4];
            #pragma unroll
            for (int qt = 0; qt < 4; qt++) {
                unsigned x0 = pa[qt][0], y0 = pb[qt][0];
                unsigned x1 = pa[qt][1], y1 = pb[qt][1];
                pl32_swap(x0, y0);
                pl32_swap(x1, y1);
                pl16_swap(x0, y0);   // x0 = W0 (k 8q+0,1), y0 = W2 (k 8q+4,5)
                pl16_swap(x1, y1);   // x1 = W1 (k 8q+2,3), y1 = W3 (k 8q+6,7)
                uint4 wd; wd.x = x0; wd.y = x1; wd.z = y0; wd.w = y1;
                pw[qt] = __builtin_bit_cast(bf16x8, wd);
            }

            // PV at K=32: vf (A-operand, A[row=d=l15][k=quad*8+i]) shared by
            // all 4 query-tiles.  O layout matches prior rounds.
            #pragma unroll
            for (int dt = 0; dt < 4; dt++) {
                bf16x8 vf = *(const bf16x8*)&Vt[dt * 16 + l15][jp * 32 + quad * 8];
                #pragma unroll
                for (int qt = 0; qt < 4; qt++)
                    o_acc[dt][qt] = __builtin_amdgcn_mfma_f32_16x16x32_bf16(vf, pw[qt], o_acc[dt][qt], 0, 0, 0);
            }
        }
    }

    // l: reduce across quads (disjoint key subsets per quad)
    #pragma unroll
    for (int qt = 0; qt < 4; qt++) {
        float v = l_part[qt];
        v += __shfl_xor(v, 16, 64);
        v += __shfl_xor(v, 32, 64);
        if (quad == 0)
            lpart[(size_t)sp * NH * N_CTX + (size_t)h * N_CTX
                  + qbase + w * 64 + qt * 16 + l15] = v;
    }

    // O partial (pre-division), bf16 [sp][N][DIM]
    #pragma unroll
    for (int qt = 0; qt < 4; qt++)
        #pragma unroll
        for (int dt = 0; dt < 4; dt++) {
            f32x4 o = o_acc[dt][qt];
            ushort4 ov;
            ov.x = f2bf(o.x); ov.y = f2bf(o.y);
            ov.z = f2bf(o.z); ov.w = f2bf(o.w);
            *(ushort4*)&opart[((size_t)sp * N_CTX + qbase + w * 64 + qt * 16 + l15) * DIM
                              + h * DH + dt * 16 + quad * 4] = ov;
        }
}

// ---------------------------------------------------------------------------
// combine: attnb[n][c] = bf16( (sum_sp O_sp)[n][c] / (sum_sp l_sp)[n,h] )
// ---------------------------------------------------------------------------
__global__ __launch_bounds__(256) void combine_kernel(
    const ushort* __restrict__ opart, const float* __restrict__ lpart,
    ushort* __restrict__ attnb)
{
    const int idx = blockIdx.x * 256 + threadIdx.x;   // one per 4 elements
    const int n   = idx >> 8;
    const int rem = idx & 255;
    const int h   = rem >> 4;
    const size_t e = (size_t)n * DIM + h * DH + (rem & 15) * 4;

    float s0 = 0.f, s1 = 0.f, s2 = 0.f, s3 = 0.f, lsum = 0.f;
    #pragma unroll
    for (int sp = 0; sp < NSPLIT; sp++) {
        ushort4 u = *(const ushort4*)&opart[(size_t)sp * N_CTX * DIM + e];
        s0 += bf2f(u.x); s1 += bf2f(u.y); s2 += bf2f(u.z); s3 += bf2f(u.w);
        lsum += lpart[(size_t)sp * NH * N_CTX + (size_t)h * N_CTX + n];
    }
    float li = 1.0f / lsum;

    ushort4 r;
    r.x = f2bf(s0 * li); r.y = f2bf(s1 * li);
    r.z = f2bf(s2 * li); r.w = f2bf(s3 * li);
    *(ushort4*)&attnb[e] = r;
}

// ---------------------------------------------------------------------------
// proj (MFMA): out[n][o] = sum_c A[n][c] * W[o][c] + b[o]
// 64x64 block tile, grid (64,16) = 1024 blocks = 4/CU.
// Double-buffer / single-barrier structure (round 5, neutral-verified).
// ---------------------------------------------------------------------------
__global__ __launch_bounds__(256) void proj_kernel(
    const ushort* __restrict__ A, const ushort* __restrict__ W,
    const float* __restrict__ bias, float* __restrict__ out)
{
    __shared__ ushort As[2][64][72];
    __shared__ ushort Ws[2][64][72];

    const int nbase = blockIdx.x * 64;
    const int obase = blockIdx.y * 64;
    const int t    = threadIdx.x;
    const int w    = t >> 6;
    const int lane = t & 63;
    const int l15  = lane & 15;
    const int quad = lane >> 4;
    const int rw   = (w >> 1) * 32;
    const int cw   = (w & 1) * 32;

    f32x4 acc[2][2];
    #pragma unroll
    for (int mt = 0; mt < 2; mt++)
        #pragma unroll
        for (int nt = 0; nt < 2; nt++)
            acc[mt][nt] = (f32x4){0.f, 0.f, 0.f, 0.f};

    // staging: rows sr, sr+32 of the 64-row K-slab, 16B per chunk
    const int sr = t >> 3;
    const int sc = (t & 7) * 8;
    const ushort* ap0 = &A[(size_t)(nbase + sr) * DIM + sc];
    const ushort* ap1 = ap0 + (size_t)32 * DIM;
    const ushort* wp0 = &W[(size_t)(obase + sr) * DIM + sc];
    const ushort* wp1 = wp0 + (size_t)32 * DIM;

    bf16x8 ar0 = *(const bf16x8*)ap0, ar1 = *(const bf16x8*)ap1;
    bf16x8 wr0 = *(const bf16x8*)wp0, wr1 = *(const bf16x8*)wp1;
    ap0 += 64; ap1 += 64; wp0 += 64; wp1 += 64;
    *(bf16x8*)&As[0][sr][sc]      = ar0;
    *(bf16x8*)&As[0][sr + 32][sc] = ar1;
    *(bf16x8*)&Ws[0][sr][sc]      = wr0;
    *(bf16x8*)&Ws[0][sr + 32][sc] = wr1;
    __syncthreads();

    for (int kt = 0; kt < DIM / 64; kt++) {
        const int cur = kt & 1;
        const bool more = (kt + 1 < DIM / 64);
        if (more) {
            ar0 = *(const bf16x8*)ap0;  ap0 += 64;
            ar1 = *(const bf16x8*)ap1;  ap1 += 64;
            wr0 = *(const bf16x8*)wp0;  wp0 += 64;
            wr1 = *(const bf16x8*)wp1;  wp1 += 64;
        }

        bf16x8 af[2][2], bfr[2][2];
        #pragma unroll
        for (int mt = 0; mt < 2; mt++)
            #pragma unroll
            for (int kh = 0; kh < 2; kh++)
                af[mt][kh] = *(const bf16x8*)&As[cur][rw + mt * 16 + l15][kh * 32 + quad * 8];
        #pragma unroll
        for (int nt = 0; nt < 2; nt++)
            #pragma unroll
            for (int kh = 0; kh < 2; kh++)
                bfr[nt][kh] = *(const bf16x8*)&Ws[cur][cw + nt * 16 + l15][kh * 32 + quad * 8];

        #pragma unroll
        for (int mt = 0; mt < 2; mt++)
            #pragma unroll
            for (int nt = 0; nt < 2; nt++) {
                acc[mt][nt] = __builtin_amdgcn_mfma_f32_16x16x32_bf16(af[mt][0], bfr[nt][0], acc[mt][nt], 0, 0, 0);
                acc[mt][nt] = __builtin_amdgcn_mfma_f32_16x16x32_bf16(af[mt][1], bfr[nt][1], acc[mt][nt], 0, 0, 0);
            }

        if (more) {
            *(bf16x8*)&As[cur ^ 1][sr][sc]      = ar0;
            *(bf16x8*)&As[cur ^ 1][sr + 32][sc] = ar1;
            *(bf16x8*)&Ws[cur ^ 1][sr][sc]      = wr0;
            *(bf16x8*)&Ws[cur ^ 1][sr + 32][sc] = wr1;
            __syncthreads();
        }
    }

    #pragma unroll
    for (int nt = 0; nt < 2; nt++) {
        int o = obase + cw + nt * 16 + l15;
        float bb = bias[o];
        #pragma unroll
        for (int mt = 0; mt < 2; mt++) {
            int nrow = nbase + rw + mt * 16 + quad * 4;
            out[(size_t)(nrow + 0) * DIM + o] = acc[mt][nt].x + bb;
            out[(size_t)(nrow + 1) * DIM + o] = acc[mt][nt].y + bb;
            out[(size_t)(nrow + 2) * DIM + o] = acc[mt][nt].z + bb;
            out[(size_t)(nrow + 3) * DIM + o] = acc[mt][nt].w + bb;
        }
    }
}

// ---------------------------------------------------------------------------
extern "C" void kernel_launch(void* const* d_in, const int* in_sizes, int n_in,
                              void* d_out, int out_size, void* d_ws, size_t ws_size,
                              hipStream_t stream)
{
    const float* q        = (const float*)d_in[0];
    const float* k        = (const float*)d_in[1];
    const float* v        = (const float*)d_in[2];
    const float* qk_scale = (const float*)d_in[3];
    const float* w_out    = (const float*)d_in[4];
    const float* b_out    = (const float*)d_in[5];
    float* out = (float*)d_out;

    const size_t per = (size_t)NH * N_CTX * DH;      // 4.19M elements
    ushort* qb    = (ushort*)d_ws;
    ushort* kb    = qb + per;
    ushort* vtg   = kb + per;
    ushort* attnb = vtg + per;                       // (N, DIM) bf16
    ushort* wb    = attnb + per;                     // (DIM, DIM) bf16
    ushort* opart = wb + (size_t)DIM * DIM;          // NSPLIT x (N, DIM) bf16
    float*  lpart = (float*)(opart + (size_t)NSPLIT * N_CTX * DIM);
    float*  ct    = lpart + (size_t)NSPLIT * NH * N_CTX;   // rope cos table
    float*  st    = ct + (size_t)N_CTX * 32;               // rope sin table

    rope_table_kernel<<<dim3(N_CTX * 32 / 256), 256, 0, stream>>>(ct, st);
    prep_kernel<<<dim3(N_CTX * NH / 4, 2), 256, 0, stream>>>(q, k, qk_scale, ct, st, qb, kb);
    vtrans_kernel<<<dim3(N_CTX / 64, NH), 256, 0, stream>>>(v, vtg);
    wconv_kernel<<<dim3(DIM * DIM / 1024), 256, 0, stream>>>(w_out, wb);
    attn_kernel<<<dim3(N_CTX / 256, NH, NSPLIT), 256, 0, stream>>>(qb, kb, vtg, opart, lpart);
    combine_kernel<<<dim3(N_CTX * DIM / 4 / 256), 256, 0, stream>>>(opart, lpart, attnb);
    proj_kernel<<<dim3(N_CTX / 64, DIM / 64), 256, 0, stream>>>(attnb, wb, b_out, out);
}

// Round 8
// 235.606 us; speedup vs baseline: 1.0229x; 1.0116x over previous
//
#include <hip/hip_runtime.h>
#include <hip/hip_bf16.h>

#define N_CTX 4096
#define NH    16
#define DH    64
#define DIM   1024   // NH * DH
#define NSPLIT 4
#define KT_PER_SPLIT (N_CTX / 64 / NSPLIT)   // 16

typedef __attribute__((ext_vector_type(8))) short bf16x8;  // 8 bf16 in 4 VGPRs
typedef __attribute__((ext_vector_type(4))) float f32x4;   // MFMA C/D
typedef __attribute__((ext_vector_type(2))) unsigned u32x2;

// RNE float->bf16 (non-hot paths)
__device__ __forceinline__ ushort f2bf(float f) {
    union { float f; unsigned u; } x; x.f = f;
    unsigned r = (x.u + 0x7FFFu + ((x.u >> 16) & 1u)) >> 16;
    return (ushort)r;
}
__device__ __forceinline__ float bf2f(ushort u) {
    union { unsigned u; float f; } x; x.u = ((unsigned)u) << 16; return x.f;
}
__device__ __forceinline__ unsigned fbits(float f) {
    union { float f; unsigned u; } x; x.f = f; return x.u;
}
// pack two floats to packed bf16 pair (round-half-up), 3 VALU ops.
// VERIFIED R0-R6.  (R7's v_cvt_pk_bf16_f32 swap regressed absmax 20x —
// rounding/packing semantics mismatch; guide m240 warned against hand-written
// cvt_pk.  Do not re-attempt without an isolated numeric probe.)
__device__ __forceinline__ unsigned pack_bf16(float lo, float hi) {
    unsigned a = fbits(lo) + 0x8000u;
    unsigned b = fbits(hi) + 0x8000u;
#if defined(__has_builtin)
#if __has_builtin(__builtin_amdgcn_perm)
    return __builtin_amdgcn_perm(b, a, 0x07060302u);
#else
    return (a >> 16) | (b & 0xFFFF0000u);
#endif
#else
    return (a >> 16) | (b & 0xFFFF0000u);
#endif
}
__device__ __forceinline__ float fast_exp2(float x) {
#if defined(__has_builtin)
#if __has_builtin(__builtin_amdgcn_exp2f)
    return __builtin_amdgcn_exp2f(x);
#else
    return exp2f(x);
#endif
#else
    return exp2f(x);
#endif
}
// hw sin/cos of x (radians): revolutions + v_fract + v_sin/v_cos.
__device__ __forceinline__ void fast_sincos(float ang, float* s, float* c) {
#if defined(__has_builtin)
#if __has_builtin(__builtin_amdgcn_sinf) && __has_builtin(__builtin_amdgcn_cosf) && __has_builtin(__builtin_amdgcn_fractf)
    float rev = __builtin_amdgcn_fractf(ang * 0.15915494309189535f);
    *s = __builtin_amdgcn_sinf(rev);
    *c = __builtin_amdgcn_cosf(rev);
    return;
#endif
#endif
    sincosf(ang, s, c);
}

// Cross-lane row swaps (gfx950 VALU ops, 2 outputs per instruction).
__device__ __forceinline__ void pl32_swap(unsigned &a, unsigned &b) {
#if defined(__has_builtin)
#if __has_builtin(__builtin_amdgcn_permlane32_swap)
    u32x2 r = __builtin_amdgcn_permlane32_swap(a, b, false, false);
    a = r[0]; b = r[1];
    return;
#endif
#endif
    const int lane = (int)(threadIdx.x & 63);
    unsigned ax = (unsigned)__shfl_xor((int)a, 32, 64);
    unsigned bx = (unsigned)__shfl_xor((int)b, 32, 64);
    unsigned na = (lane & 32) ? bx : a;
    unsigned nb = (lane & 32) ? b  : ax;
    a = na; b = nb;
}
__device__ __forceinline__ void pl16_swap(unsigned &a, unsigned &b) {
#if defined(__has_builtin)
#if __has_builtin(__builtin_amdgcn_permlane16_swap)
    u32x2 r = __builtin_amdgcn_permlane16_swap(a, b, false, false);
    a = r[0]; b = r[1];
    return;
#endif
#endif
    const int lane = (int)(threadIdx.x & 63);
    unsigned ax = (unsigned)__shfl_xor((int)a, 16, 64);
    unsigned bx = (unsigned)__shfl_xor((int)b, 16, 64);
    unsigned na = (lane & 16) ? bx : a;
    unsigned nb = (lane & 16) ? b  : ax;
    a = na; b = nb;
}

// 0.125 * log2(e): folded into Q during prep; softmax shift-invariance lets us
// drop the bias term entirely (p = exp2(s) directly, p <= 2^18.1).
#define SC 0.18033688011112042f
// log2(10000)/32
#define LF 0.4152410118609203f

// ---------------------------------------------------------------------------
// rope_table: cos/sin of n * 10000^(-i/32) for (n,i) in N_CTX x 32, f32.
// ---------------------------------------------------------------------------
__global__ __launch_bounds__(256) void rope_table_kernel(
    float* __restrict__ ct, float* __restrict__ st)
{
    const int idx = blockIdx.x * 256 + threadIdx.x;   // n*32 + i
    const int n = idx >> 5, i = idx & 31;
    float inv_freq = fast_exp2((float)i * -LF);       // 10000^(-i/32)
    float s, c;
    fast_sincos((float)n * inv_freq, &s, &c);
    ct[idx] = c; st[idx] = s;
}

// ---------------------------------------------------------------------------
// prep (fused q+k): x (N, DIM) fp32 -> rope (table) -> l2norm -> * qk_scale *
//       premul -> xb bf16 [h][n][d].  blockIdx.y: 0 = q (premul SC), 1 = k.
// ---------------------------------------------------------------------------
__global__ __launch_bounds__(256) void prep_kernel(
    const float* __restrict__ qg, const float* __restrict__ kg,
    const float* __restrict__ qk_scale,
    const float* __restrict__ ct, const float* __restrict__ st,
    ushort* __restrict__ qb, ushort* __restrict__ kb)
{
    const int lane = threadIdx.x & 63;
    const int wave = threadIdx.x >> 6;
    const int row  = blockIdx.x * 4 + wave;   // row = n*NH + h
    const int n = row >> 4;
    const int h = row & 15;
    const int isk = blockIdx.y;
    const float* __restrict__ x = isk ? kg : qg;
    ushort* __restrict__ xb = isk ? kb : qb;
    const float premul = isk ? 1.0f : SC;

    float val = x[(size_t)n * DIM + h * DH + lane];
    float other = __shfl_xor(val, 1, 64);

    const int i = lane >> 1;
    const float c = ct[(n << 5) | i];
    const float s = st[(n << 5) | i];

    float r = (lane & 1) ? fmaf(other, s, val * c)
                         : fmaf(val, c, -(other * s));

    float ss = r * r;
    #pragma unroll
    for (int off = 32; off > 0; off >>= 1)
        ss += __shfl_xor(ss, off, 64);
    float invn = rsqrtf(fmaxf(ss, 1e-24f));
    float scl  = qk_scale[lane] * premul;

    xb[((size_t)h * N_CTX + n) * DH + lane] = f2bf(r * invn * scl);
}

// ---------------------------------------------------------------------------
// vtrans: v (N, DIM) fp32 -> vt bf16 [h][d][n]
// ---------------------------------------------------------------------------
__global__ __launch_bounds__(256) void vtrans_kernel(
    const float* __restrict__ v, ushort* __restrict__ vt)
{
    __shared__ ushort L[64][68];
    const int kt = blockIdx.x, h = blockIdx.y, t = threadIdx.x;

    for (int e = t; e < 4096; e += 256) {
        int key = e >> 6, d = e & 63;
        float f = v[(size_t)(kt * 64 + key) * DIM + h * DH + d];
        L[d][key] = f2bf(f);
    }
    __syncthreads();
    for (int e = t; e < 4096; e += 256) {
        int d = e >> 6, key = e & 63;
        vt[((size_t)h * DH + d) * N_CTX + kt * 64 + key] = L[d][key];
    }
}

// ---------------------------------------------------------------------------
// wconv: w_out (DIM, DIM) fp32 -> bf16 row-major
// ---------------------------------------------------------------------------
__global__ __launch_bounds__(256) void wconv_kernel(
    const float* __restrict__ w, ushort* __restrict__ wb)
{
    int i = (blockIdx.x * 256 + threadIdx.x) * 4;
    float4 f = *(const float4*)&w[i];
    ushort4 u;
    u.x = f2bf(f.x); u.y = f2bf(f.y); u.z = f2bf(f.z); u.w = f2bf(f.w);
    *(ushort4*)&wb[i] = u;
}

// ---------------------------------------------------------------------------
// attn: MFMA flash attention, P in registers, K=32 PV via permlane assembly.
// 4 query-tiles per wave (R6, verified: bank-conflict halved exactly).
// R8: reverted R7's cvt_pk experiment back to verified pack_bf16.
// NOTE: no min-waves launch bound — caps spill o_acc (round 1: 970 MB
// scratch writes).  WRITE_SIZE == 33792 KB is the no-spill tripwire.
// ---------------------------------------------------------------------------
__global__ __launch_bounds__(256) void attn_kernel(
    const ushort* __restrict__ qb, const ushort* __restrict__ kb,
    const ushort* __restrict__ vt, ushort* __restrict__ opart,
    float* __restrict__ lpart)
{
    __shared__ ushort Ks[64][72];    // [key][d]
    __shared__ ushort Vt[64][72];    // [d][key]

    const int h     = blockIdx.y;
    const int qbase = blockIdx.x * 256;
    const int sp    = blockIdx.z;
    const int kbase = sp * (N_CTX / NSPLIT);
    const int t    = threadIdx.x;
    const int w    = t >> 6;
    const int lane = t & 63;
    const int l15  = lane & 15;
    const int quad = lane >> 4;

    // Q B-fragments: 4 query-tiles x 2 k-halves (queries w*64 + qt*16 + l15)
    bf16x8 qf[4][2];
    #pragma unroll
    for (int qt = 0; qt < 4; qt++) {
        const size_t qrow = ((size_t)h * N_CTX + qbase + w * 64 + qt * 16 + l15) * DH;
        qf[qt][0] = *(const bf16x8*)&qb[qrow + quad * 8];
        qf[qt][1] = *(const bf16x8*)&qb[qrow + 32 + quad * 8];
    }

    float l_part[4] = {0.f, 0.f, 0.f, 0.f};
    f32x4 o_acc[4][4];               // [dt][qt]
    #pragma unroll
    for (int dt = 0; dt < 4; dt++)
        #pragma unroll
        for (int qt = 0; qt < 4; qt++)
            o_acc[dt][qt] = (f32x4){0.f, 0.f, 0.f, 0.f};

    // staging: 256 threads, 2 x 16B chunks each of K and V (rows sr, sr+32)
    const int sr = t >> 3;
    const int sc = (t & 7) * 8;
    const ushort* kp0 = &kb[((size_t)h * N_CTX + kbase + sr) * DH + sc];
    const ushort* kp1 = kp0 + (size_t)32 * DH;
    const ushort* vp0 = &vt[((size_t)h * DH + sr) * N_CTX + kbase + sc];
    const ushort* vp1 = vp0 + (size_t)32 * N_CTX;
    bf16x8 kr0 = *(const bf16x8*)kp0, kr1 = *(const bf16x8*)kp1;
    bf16x8 vr0 = *(const bf16x8*)vp0, vr1 = *(const bf16x8*)vp1;

    for (int kt = 0; kt < KT_PER_SPLIT; kt++) {
        __syncthreads();                       // A: all waves done with prev tile
        *(bf16x8*)&Ks[sr][sc]      = kr0;
        *(bf16x8*)&Ks[sr + 32][sc] = kr1;
        *(bf16x8*)&Vt[sr][sc]      = vr0;
        *(bf16x8*)&Vt[sr + 32][sc] = vr1;
        __syncthreads();                       // B: staging visible
        if (kt + 1 < KT_PER_SPLIT) {           // prefetch next tile into regs
            kr0 = *(const bf16x8*)(kp0 + (size_t)(kt + 1) * 64 * DH);
            kr1 = *(const bf16x8*)(kp1 + (size_t)(kt + 1) * 64 * DH);
            vr0 = *(const bf16x8*)(vp0 + (size_t)(kt + 1) * 64);
            vr1 = *(const bf16x8*)(vp1 + (size_t)(kt + 1) * 64);
        }

        // ---- fused S+PV over 2 key-subtile PAIRS (32 keys each)
        #pragma unroll
        for (int jp = 0; jp < 2; jp++) {
            unsigned pa[4][2], pb[4][2];   // [qt][dword]: subtile jj=0 / jj=1
            #pragma unroll
            for (int jj = 0; jj < 2; jj++) {
                const int j = jp * 2 + jj;
                bf16x8 kf0 = *(const bf16x8*)&Ks[j * 16 + l15][quad * 8];
                bf16x8 kf1 = *(const bf16x8*)&Ks[j * 16 + l15][32 + quad * 8];
                f32x4 sv[4];
                #pragma unroll
                for (int qt = 0; qt < 4; qt++)
                    sv[qt] = (f32x4){0.f, 0.f, 0.f, 0.f};
                #pragma unroll
                for (int qt = 0; qt < 4; qt++)
                    sv[qt] = __builtin_amdgcn_mfma_f32_16x16x32_bf16(kf0, qf[qt][0], sv[qt], 0, 0, 0);
                #pragma unroll
                for (int qt = 0; qt < 4; qt++)
                    sv[qt] = __builtin_amdgcn_mfma_f32_16x16x32_bf16(kf1, qf[qt][1], sv[qt], 0, 0, 0);

                #pragma unroll
                for (int qt = 0; qt < 4; qt++) {
                    float p0 = fast_exp2(sv[qt].x), p1 = fast_exp2(sv[qt].y);
                    float p2 = fast_exp2(sv[qt].z), p3 = fast_exp2(sv[qt].w);
                    l_part[qt] += (p0 + p1) + (p2 + p3);
                    unsigned d0 = pack_bf16(p0, p1), d1 = pack_bf16(p2, p3);
                    if (jj == 0) { pa[qt][0] = d0; pa[qt][1] = d1; }
                    else         { pb[qt][0] = d0; pb[qt][1] = d1; }
                }
            }

            // assemble K=32 B-fragments in-register (4 permlane ops per qt)
            bf16x8 pw[4];
            #pragma unroll
            for (int qt = 0; qt < 4; qt++) {
                unsigned x0 = pa[qt][0], y0 = pb[qt][0];
                unsigned x1 = pa[qt][1], y1 = pb[qt][1];
                pl32_swap(x0, y0);
                pl32_swap(x1, y1);
                pl16_swap(x0, y0);   // x0 = W0 (k 8q+0,1), y0 = W2 (k 8q+4,5)
                pl16_swap(x1, y1);   // x1 = W1 (k 8q+2,3), y1 = W3 (k 8q+6,7)
                uint4 wd; wd.x = x0; wd.y = x1; wd.z = y0; wd.w = y1;
                pw[qt] = __builtin_bit_cast(bf16x8, wd);
            }

            // PV at K=32: vf (A-operand, A[row=d=l15][k=quad*8+i]) shared by
            // all 4 query-tiles.  O layout matches prior rounds.
            #pragma unroll
            for (int dt = 0; dt < 4; dt++) {
                bf16x8 vf = *(const bf16x8*)&Vt[dt * 16 + l15][jp * 32 + quad * 8];
                #pragma unroll
                for (int qt = 0; qt < 4; qt++)
                    o_acc[dt][qt] = __builtin_amdgcn_mfma_f32_16x16x32_bf16(vf, pw[qt], o_acc[dt][qt], 0, 0, 0);
            }
        }
    }

    // l: reduce across quads (disjoint key subsets per quad)
    #pragma unroll
    for (int qt = 0; qt < 4; qt++) {
        float v = l_part[qt];
        v += __shfl_xor(v, 16, 64);
        v += __shfl_xor(v, 32, 64);
        if (quad == 0)
            lpart[(size_t)sp * NH * N_CTX + (size_t)h * N_CTX
                  + qbase + w * 64 + qt * 16 + l15] = v;
    }

    // O partial (pre-division), bf16 [sp][N][DIM]
    #pragma unroll
    for (int qt = 0; qt < 4; qt++)
        #pragma unroll
        for (int dt = 0; dt < 4; dt++) {
            f32x4 o = o_acc[dt][qt];
            ushort4 ov;
            ov.x = f2bf(o.x); ov.y = f2bf(o.y);
            ov.z = f2bf(o.z); ov.w = f2bf(o.w);
            *(ushort4*)&opart[((size_t)sp * N_CTX + qbase + w * 64 + qt * 16 + l15) * DIM
                              + h * DH + dt * 16 + quad * 4] = ov;
        }
}

// ---------------------------------------------------------------------------
// combine: attnb[n][c] = bf16( (sum_sp O_sp)[n][c] / (sum_sp l_sp)[n,h] )
// ---------------------------------------------------------------------------
__global__ __launch_bounds__(256) void combine_kernel(
    const ushort* __restrict__ opart, const float* __restrict__ lpart,
    ushort* __restrict__ attnb)
{
    const int idx = blockIdx.x * 256 + threadIdx.x;   // one per 4 elements
    const int n   = idx >> 8;
    const int rem = idx & 255;
    const int h   = rem >> 4;
    const size_t e = (size_t)n * DIM + h * DH + (rem & 15) * 4;

    float s0 = 0.f, s1 = 0.f, s2 = 0.f, s3 = 0.f, lsum = 0.f;
    #pragma unroll
    for (int sp = 0; sp < NSPLIT; sp++) {
        ushort4 u = *(const ushort4*)&opart[(size_t)sp * N_CTX * DIM + e];
        s0 += bf2f(u.x); s1 += bf2f(u.y); s2 += bf2f(u.z); s3 += bf2f(u.w);
        lsum += lpart[(size_t)sp * NH * N_CTX + (size_t)h * N_CTX + n];
    }
    float li = 1.0f / lsum;

    ushort4 r;
    r.x = f2bf(s0 * li); r.y = f2bf(s1 * li);
    r.z = f2bf(s2 * li); r.w = f2bf(s3 * li);
    *(ushort4*)&attnb[e] = r;
}

// ---------------------------------------------------------------------------
// proj (MFMA): out[n][o] = sum_c A[n][c] * W[o][c] + b[o]
// 128x128 block tile (m93-class): 2:1 MFMA:ds_read, acc[4][4]/wave.
// Grid (32,8) = 256 blocks = exactly 1/CU, no tail.  Bit-identical
// accumulation order to the verified 64x64 kernel (same K-slab sequence).
// ---------------------------------------------------------------------------
__global__ __launch_bounds__(256) void proj_kernel(
    const ushort* __restrict__ A, const ushort* __restrict__ W,
    const float* __restrict__ bias, float* __restrict__ out)
{
    __shared__ ushort As[128][72];
    __shared__ ushort Ws[128][72];

    const int nbase = blockIdx.x * 128;
    const int obase = blockIdx.y * 128;
    const int t    = threadIdx.x;
    const int w    = t >> 6;
    const int lane = t & 63;
    const int l15  = lane & 15;
    const int quad = lane >> 4;
    const int rw   = (w >> 1) * 64;
    const int cw   = (w & 1) * 64;

    f32x4 acc[4][4];
    #pragma unroll
    for (int mt = 0; mt < 4; mt++)
        #pragma unroll
        for (int nt = 0; nt < 4; nt++)
            acc[mt][nt] = (f32x4){0.f, 0.f, 0.f, 0.f};

    // staging: 4 x 16B chunks each of A and W; rows srow + i*32, i<4
    const int srow = t >> 3;
    const int scol = (t & 7) * 8;
    const ushort* apt = &A[(size_t)(nbase + srow) * DIM + scol];
    const ushort* wpt = &W[(size_t)(obase + srow) * DIM + scol];

    bf16x8 ar[4], wr[4];
    #pragma unroll
    for (int i = 0; i < 4; i++) {
        ar[i] = *(const bf16x8*)(apt + (size_t)i * 32 * DIM);
        wr[i] = *(const bf16x8*)(wpt + (size_t)i * 32 * DIM);
    }

    for (int kt = 0; kt < DIM / 64; kt++) {
        __syncthreads();                       // A: prev tile fully consumed
        #pragma unroll
        for (int i = 0; i < 4; i++) {
            *(bf16x8*)&As[srow + i * 32][scol] = ar[i];
            *(bf16x8*)&Ws[srow + i * 32][scol] = wr[i];
        }
        __syncthreads();                       // B: staging visible
        if (kt + 1 < DIM / 64) {               // prefetch next K-slab
            #pragma unroll
            for (int i = 0; i < 4; i++) {
                ar[i] = *(const bf16x8*)(apt + (size_t)(kt + 1) * 64 + (size_t)i * 32 * DIM);
                wr[i] = *(const bf16x8*)(wpt + (size_t)(kt + 1) * 64 + (size_t)i * 32 * DIM);
            }
        }

        bf16x8 af[4][2], bfr[4][2];
        #pragma unroll
        for (int mt = 0; mt < 4; mt++)
            #pragma unroll
            for (int kh = 0; kh < 2; kh++)
                af[mt][kh] = *(const bf16x8*)&As[rw + mt * 16 + l15][kh * 32 + quad * 8];
        #pragma unroll
        for (int nt = 0; nt < 4; nt++)
            #pragma unroll
            for (int kh = 0; kh < 2; kh++)
                bfr[nt][kh] = *(const bf16x8*)&Ws[cw + nt * 16 + l15][kh * 32 + quad * 8];

        #pragma unroll
        for (int mt = 0; mt < 4; mt++)
            #pragma unroll
            for (int nt = 0; nt < 4; nt++) {
                acc[mt][nt] = __builtin_amdgcn_mfma_f32_16x16x32_bf16(af[mt][0], bfr[nt][0], acc[mt][nt], 0, 0, 0);
                acc[mt][nt] = __builtin_amdgcn_mfma_f32_16x16x32_bf16(af[mt][1], bfr[nt][1], acc[mt][nt], 0, 0, 0);
            }
    }

    #pragma unroll
    for (int nt = 0; nt < 4; nt++) {
        int o = obase + cw + nt * 16 + l15;
        float bb = bias[o];
        #pragma unroll
        for (int mt = 0; mt < 4; mt++) {
            int nrow = nbase + rw + mt * 16 + quad * 4;
            out[(size_t)(nrow + 0) * DIM + o] = acc[mt][nt].x + bb;
            out[(size_t)(nrow + 1) * DIM + o] = acc[mt][nt].y + bb;
            out[(size_t)(nrow + 2) * DIM + o] = acc[mt][nt].z + bb;
            out[(size_t)(nrow + 3) * DIM + o] = acc[mt][nt].w + bb;
        }
    }
}

// ---------------------------------------------------------------------------
extern "C" void kernel_launch(void* const* d_in, const int* in_sizes, int n_in,
                              void* d_out, int out_size, void* d_ws, size_t ws_size,
                              hipStream_t stream)
{
    const float* q        = (const float*)d_in[0];
    const float* k        = (const float*)d_in[1];
    const float* v        = (const float*)d_in[2];
    const float* qk_scale = (const float*)d_in[3];
    const float* w_out    = (const float*)d_in[4];
    const float* b_out    = (const float*)d_in[5];
    float* out = (float*)d_out;

    const size_t per = (size_t)NH * N_CTX * DH;      // 4.19M elements
    ushort* qb    = (ushort*)d_ws;
    ushort* kb    = qb + per;
    ushort* vtg   = kb + per;
    ushort* attnb = vtg + per;                       // (N, DIM) bf16
    ushort* wb    = attnb + per;                     // (DIM, DIM) bf16
    ushort* opart = wb + (size_t)DIM * DIM;          // NSPLIT x (N, DIM) bf16
    float*  lpart = (float*)(opart + (size_t)NSPLIT * N_CTX * DIM);
    float*  ct    = lpart + (size_t)NSPLIT * NH * N_CTX;   // rope cos table
    float*  st    = ct + (size_t)N_CTX * 32;               // rope sin table

    rope_table_kernel<<<dim3(N_CTX * 32 / 256), 256, 0, stream>>>(ct, st);
    prep_kernel<<<dim3(N_CTX * NH / 4, 2), 256, 0, stream>>>(q, k, qk_scale, ct, st, qb, kb);
    vtrans_kernel<<<dim3(N_CTX / 64, NH), 256, 0, stream>>>(v, vtg);
    wconv_kernel<<<dim3(DIM * DIM / 1024), 256, 0, stream>>>(w_out, wb);
    attn_kernel<<<dim3(N_CTX / 256, NH, NSPLIT), 256, 0, stream>>>(qb, kb, vtg, opart, lpart);
    combine_kernel<<<dim3(N_CTX * DIM / 4 / 256), 256, 0, stream>>>(opart, lpart, attnb);
    proj_kernel<<<dim3(N_CTX / 128, DIM / 128), 256, 0, stream>>>(attnb, wb, b_out, out);
}

// Round 9
// 234.095 us; speedup vs baseline: 1.0295x; 1.0065x over previous
//
#include <hip/hip_runtime.h>
#include <hip/hip_bf16.h>

#define N_CTX 4096
#define NH    16
#define DH    64
#define DIM   1024   // NH * DH
#define NSPLIT 4
#define KT_PER_SPLIT (N_CTX / 64 / NSPLIT)   // 16

typedef __attribute__((ext_vector_type(8))) short bf16x8;  // 8 bf16 in 4 VGPRs
typedef __attribute__((ext_vector_type(4))) float f32x4;   // MFMA C/D
typedef __attribute__((ext_vector_type(2))) unsigned u32x2;

// RNE float->bf16 (non-hot paths)
__device__ __forceinline__ ushort f2bf(float f) {
    union { float f; unsigned u; } x; x.f = f;
    unsigned r = (x.u + 0x7FFFu + ((x.u >> 16) & 1u)) >> 16;
    return (ushort)r;
}
__device__ __forceinline__ float bf2f(ushort u) {
    union { unsigned u; float f; } x; x.u = ((unsigned)u) << 16; return x.f;
}
__device__ __forceinline__ unsigned fbits(float f) {
    union { float f; unsigned u; } x; x.f = f; return x.u;
}
// pack two floats to packed bf16 pair (round-half-up), 3 VALU ops.
// VERIFIED R0-R8.  (R7's v_cvt_pk_bf16_f32 swap regressed absmax 20x —
// rounding/packing semantics mismatch; do not re-attempt without an isolated
// numeric probe.)
__device__ __forceinline__ unsigned pack_bf16(float lo, float hi) {
    unsigned a = fbits(lo) + 0x8000u;
    unsigned b = fbits(hi) + 0x8000u;
#if defined(__has_builtin)
#if __has_builtin(__builtin_amdgcn_perm)
    return __builtin_amdgcn_perm(b, a, 0x07060302u);
#else
    return (a >> 16) | (b & 0xFFFF0000u);
#endif
#else
    return (a >> 16) | (b & 0xFFFF0000u);
#endif
}
__device__ __forceinline__ float fast_exp2(float x) {
#if defined(__has_builtin)
#if __has_builtin(__builtin_amdgcn_exp2f)
    return __builtin_amdgcn_exp2f(x);
#else
    return exp2f(x);
#endif
#else
    return exp2f(x);
#endif
}
// hw sin/cos of x (radians): revolutions + v_fract + v_sin/v_cos.
__device__ __forceinline__ void fast_sincos(float ang, float* s, float* c) {
#if defined(__has_builtin)
#if __has_builtin(__builtin_amdgcn_sinf) && __has_builtin(__builtin_amdgcn_cosf) && __has_builtin(__builtin_amdgcn_fractf)
    float rev = __builtin_amdgcn_fractf(ang * 0.15915494309189535f);
    *s = __builtin_amdgcn_sinf(rev);
    *c = __builtin_amdgcn_cosf(rev);
    return;
#endif
#endif
    sincosf(ang, s, c);
}

// Cross-lane row swaps (gfx950 VALU ops, 2 outputs per instruction).
__device__ __forceinline__ void pl32_swap(unsigned &a, unsigned &b) {
#if defined(__has_builtin)
#if __has_builtin(__builtin_amdgcn_permlane32_swap)
    u32x2 r = __builtin_amdgcn_permlane32_swap(a, b, false, false);
    a = r[0]; b = r[1];
    return;
#endif
#endif
    const int lane = (int)(threadIdx.x & 63);
    unsigned ax = (unsigned)__shfl_xor((int)a, 32, 64);
    unsigned bx = (unsigned)__shfl_xor((int)b, 32, 64);
    unsigned na = (lane & 32) ? bx : a;
    unsigned nb = (lane & 32) ? b  : ax;
    a = na; b = nb;
}
__device__ __forceinline__ void pl16_swap(unsigned &a, unsigned &b) {
#if defined(__has_builtin)
#if __has_builtin(__builtin_amdgcn_permlane16_swap)
    u32x2 r = __builtin_amdgcn_permlane16_swap(a, b, false, false);
    a = r[0]; b = r[1];
    return;
#endif
#endif
    const int lane = (int)(threadIdx.x & 63);
    unsigned ax = (unsigned)__shfl_xor((int)a, 16, 64);
    unsigned bx = (unsigned)__shfl_xor((int)b, 16, 64);
    unsigned na = (lane & 16) ? bx : a;
    unsigned nb = (lane & 16) ? b  : ax;
    a = na; b = nb;
}

// 0.125 * log2(e): folded into Q during prep; softmax shift-invariance lets us
// drop the bias term entirely (p = exp2(s) directly, p <= 2^18.1).
#define SC 0.18033688011112042f
// log2(10000)/32
#define LF 0.4152410118609203f

// ---------------------------------------------------------------------------
// front (fused): prep-q | prep-k | vtrans | wconv in ONE launch.
// These four are mutually independent; R5->R6 evidence shows each kernel
// boundary costs ~5-8 µs (dispatch + cross-XCD cache drain), and the
// non-attn gap (132 µs observed vs ~60 µs BW floor) points at boundaries.
// Branch is block-uniform (on blockIdx.x), so vtrans's barrier is legal.
//   bid [0,16384)      : prep q  (premul SC)
//   bid [16384,32768)  : prep k
//   bid [32768,33792)  : vtrans (kt = b&63, h = b>>6)
//   bid [33792,34816)  : wconv
// ---------------------------------------------------------------------------
__global__ __launch_bounds__(256) void front_kernel(
    const float* __restrict__ qg, const float* __restrict__ kg,
    const float* __restrict__ v,  const float* __restrict__ w,
    const float* __restrict__ qk_scale,
    ushort* __restrict__ qb, ushort* __restrict__ kb,
    ushort* __restrict__ vt, ushort* __restrict__ wb)
{
    __shared__ ushort L[64][68];
    const int bid = blockIdx.x;
    const int t   = threadIdx.x;

    if (bid < 32768) {
        // ---- prep (R5-verified body: per-thread sincos) ----
        const int isk  = bid >> 14;
        const int bx   = bid & 16383;
        const int lane = t & 63;
        const int wave = t >> 6;
        const int row  = bx * 4 + wave;   // row = n*NH + h
        const int n = row >> 4;
        const int h = row & 15;
        const float* __restrict__ x = isk ? kg : qg;
        ushort* __restrict__ xb = isk ? kb : qb;
        const float premul = isk ? 1.0f : SC;

        float val = x[(size_t)n * DIM + h * DH + lane];
        float other = __shfl_xor(val, 1, 64);

        const int i = lane >> 1;
        float inv_freq = fast_exp2((float)i * -LF);   // 10000^(-i/32)
        float ang = (float)n * inv_freq;
        float s, c;
        fast_sincos(ang, &s, &c);

        float r = (lane & 1) ? fmaf(other, s, val * c)
                             : fmaf(val, c, -(other * s));

        float ss = r * r;
        #pragma unroll
        for (int off = 32; off > 0; off >>= 1)
            ss += __shfl_xor(ss, off, 64);
        float invn = rsqrtf(fmaxf(ss, 1e-24f));
        float scl  = qk_scale[lane] * premul;

        xb[((size_t)h * N_CTX + n) * DH + lane] = f2bf(r * invn * scl);
    } else if (bid < 33792) {
        // ---- vtrans: v (N, DIM) fp32 -> vt bf16 [h][d][n] ----
        const int b2 = bid - 32768;
        const int kt = b2 & 63, h = b2 >> 6;

        for (int e = t; e < 4096; e += 256) {
            int key = e >> 6, d = e & 63;
            float f = v[(size_t)(kt * 64 + key) * DIM + h * DH + d];
            L[d][key] = f2bf(f);
        }
        __syncthreads();
        for (int e = t; e < 4096; e += 256) {
            int d = e >> 6, key = e & 63;
            vt[((size_t)h * DH + d) * N_CTX + kt * 64 + key] = L[d][key];
        }
    } else {
        // ---- wconv: w_out (DIM, DIM) fp32 -> bf16 row-major ----
        const int b2 = bid - 33792;
        int i = (b2 * 256 + t) * 4;
        float4 f = *(const float4*)&w[i];
        ushort4 u;
        u.x = f2bf(f.x); u.y = f2bf(f.y); u.z = f2bf(f.z); u.w = f2bf(f.w);
        *(ushort4*)&wb[i] = u;
    }
}

// ---------------------------------------------------------------------------
// attn: MFMA flash attention, P in registers, K=32 PV via permlane assembly.
// 4 query-tiles per wave (R6, verified: bank-conflict halved exactly).
// UNCHANGED from R8 (verified: 103.8 µs, VGPR 112, bank 4.19e6).
// NOTE: no min-waves launch bound — caps spill o_acc (round 1: 970 MB
// scratch writes).  WRITE_SIZE == 33792 KB is the no-spill tripwire.
// ---------------------------------------------------------------------------
__global__ __launch_bounds__(256) void attn_kernel(
    const ushort* __restrict__ qb, const ushort* __restrict__ kb,
    const ushort* __restrict__ vt, ushort* __restrict__ opart,
    float* __restrict__ lpart)
{
    __shared__ ushort Ks[64][72];    // [key][d]
    __shared__ ushort Vt[64][72];    // [d][key]

    const int h     = blockIdx.y;
    const int qbase = blockIdx.x * 256;
    const int sp    = blockIdx.z;
    const int kbase = sp * (N_CTX / NSPLIT);
    const int t    = threadIdx.x;
    const int w    = t >> 6;
    const int lane = t & 63;
    const int l15  = lane & 15;
    const int quad = lane >> 4;

    // Q B-fragments: 4 query-tiles x 2 k-halves (queries w*64 + qt*16 + l15)
    bf16x8 qf[4][2];
    #pragma unroll
    for (int qt = 0; qt < 4; qt++) {
        const size_t qrow = ((size_t)h * N_CTX + qbase + w * 64 + qt * 16 + l15) * DH;
        qf[qt][0] = *(const bf16x8*)&qb[qrow + quad * 8];
        qf[qt][1] = *(const bf16x8*)&qb[qrow + 32 + quad * 8];
    }

    float l_part[4] = {0.f, 0.f, 0.f, 0.f};
    f32x4 o_acc[4][4];               // [dt][qt]
    #pragma unroll
    for (int dt = 0; dt < 4; dt++)
        #pragma unroll
        for (int qt = 0; qt < 4; qt++)
            o_acc[dt][qt] = (f32x4){0.f, 0.f, 0.f, 0.f};

    // staging: 256 threads, 2 x 16B chunks each of K and V (rows sr, sr+32)
    const int sr = t >> 3;
    const int sc = (t & 7) * 8;
    const ushort* kp0 = &kb[((size_t)h * N_CTX + kbase + sr) * DH + sc];
    const ushort* kp1 = kp0 + (size_t)32 * DH;
    const ushort* vp0 = &vt[((size_t)h * DH + sr) * N_CTX + kbase + sc];
    const ushort* vp1 = vp0 + (size_t)32 * N_CTX;
    bf16x8 kr0 = *(const bf16x8*)kp0, kr1 = *(const bf16x8*)kp1;
    bf16x8 vr0 = *(const bf16x8*)vp0, vr1 = *(const bf16x8*)vp1;

    for (int kt = 0; kt < KT_PER_SPLIT; kt++) {
        __syncthreads();                       // A: all waves done with prev tile
        *(bf16x8*)&Ks[sr][sc]      = kr0;
        *(bf16x8*)&Ks[sr + 32][sc] = kr1;
        *(bf16x8*)&Vt[sr][sc]      = vr0;
        *(bf16x8*)&Vt[sr + 32][sc] = vr1;
        __syncthreads();                       // B: staging visible
        if (kt + 1 < KT_PER_SPLIT) {           // prefetch next tile into regs
            kr0 = *(const bf16x8*)(kp0 + (size_t)(kt + 1) * 64 * DH);
            kr1 = *(const bf16x8*)(kp1 + (size_t)(kt + 1) * 64 * DH);
            vr0 = *(const bf16x8*)(vp0 + (size_t)(kt + 1) * 64);
            vr1 = *(const bf16x8*)(vp1 + (size_t)(kt + 1) * 64);
        }

        // ---- fused S+PV over 2 key-subtile PAIRS (32 keys each)
        #pragma unroll
        for (int jp = 0; jp < 2; jp++) {
            unsigned pa[4][2], pb[4][2];   // [qt][dword]: subtile jj=0 / jj=1
            #pragma unroll
            for (int jj = 0; jj < 2; jj++) {
                const int j = jp * 2 + jj;
                bf16x8 kf0 = *(const bf16x8*)&Ks[j * 16 + l15][quad * 8];
                bf16x8 kf1 = *(const bf16x8*)&Ks[j * 16 + l15][32 + quad * 8];
                f32x4 sv[4];
                #pragma unroll
                for (int qt = 0; qt < 4; qt++)
                    sv[qt] = (f32x4){0.f, 0.f, 0.f, 0.f};
                #pragma unroll
                for (int qt = 0; qt < 4; qt++)
                    sv[qt] = __builtin_amdgcn_mfma_f32_16x16x32_bf16(kf0, qf[qt][0], sv[qt], 0, 0, 0);
                #pragma unroll
                for (int qt = 0; qt < 4; qt++)
                    sv[qt] = __builtin_amdgcn_mfma_f32_16x16x32_bf16(kf1, qf[qt][1], sv[qt], 0, 0, 0);

                #pragma unroll
                for (int qt = 0; qt < 4; qt++) {
                    float p0 = fast_exp2(sv[qt].x), p1 = fast_exp2(sv[qt].y);
                    float p2 = fast_exp2(sv[qt].z), p3 = fast_exp2(sv[qt].w);
                    l_part[qt] += (p0 + p1) + (p2 + p3);
                    unsigned d0 = pack_bf16(p0, p1), d1 = pack_bf16(p2, p3);
                    if (jj == 0) { pa[qt][0] = d0; pa[qt][1] = d1; }
                    else         { pb[qt][0] = d0; pb[qt][1] = d1; }
                }
            }

            // assemble K=32 B-fragments in-register (4 permlane ops per qt)
            bf16x8 pw[4];
            #pragma unroll
            for (int qt = 0; qt < 4; qt++) {
                unsigned x0 = pa[qt][0], y0 = pb[qt][0];
                unsigned x1 = pa[qt][1], y1 = pb[qt][1];
                pl32_swap(x0, y0);
                pl32_swap(x1, y1);
                pl16_swap(x0, y0);   // x0 = W0 (k 8q+0,1), y0 = W2 (k 8q+4,5)
                pl16_swap(x1, y1);   // x1 = W1 (k 8q+2,3), y1 = W3 (k 8q+6,7)
                uint4 wd; wd.x = x0; wd.y = x1; wd.z = y0; wd.w = y1;
                pw[qt] = __builtin_bit_cast(bf16x8, wd);
            }

            // PV at K=32: vf (A-operand, A[row=d=l15][k=quad*8+i]) shared by
            // all 4 query-tiles.  O layout matches prior rounds.
            #pragma unroll
            for (int dt = 0; dt < 4; dt++) {
                bf16x8 vf = *(const bf16x8*)&Vt[dt * 16 + l15][jp * 32 + quad * 8];
                #pragma unroll
                for (int qt = 0; qt < 4; qt++)
                    o_acc[dt][qt] = __builtin_amdgcn_mfma_f32_16x16x32_bf16(vf, pw[qt], o_acc[dt][qt], 0, 0, 0);
            }
        }
    }

    // l: reduce across quads (disjoint key subsets per quad)
    #pragma unroll
    for (int qt = 0; qt < 4; qt++) {
        float v = l_part[qt];
        v += __shfl_xor(v, 16, 64);
        v += __shfl_xor(v, 32, 64);
        if (quad == 0)
            lpart[(size_t)sp * NH * N_CTX + (size_t)h * N_CTX
                  + qbase + w * 64 + qt * 16 + l15] = v;
    }

    // O partial (pre-division), bf16 [sp][N][DIM]
    #pragma unroll
    for (int qt = 0; qt < 4; qt++)
        #pragma unroll
        for (int dt = 0; dt < 4; dt++) {
            f32x4 o = o_acc[dt][qt];
            ushort4 ov;
            ov.x = f2bf(o.x); ov.y = f2bf(o.y);
            ov.z = f2bf(o.z); ov.w = f2bf(o.w);
            *(ushort4*)&opart[((size_t)sp * N_CTX + qbase + w * 64 + qt * 16 + l15) * DIM
                              + h * DH + dt * 16 + quad * 4] = ov;
        }
}

// ---------------------------------------------------------------------------
// combine: attnb[n][c] = bf16( (sum_sp O_sp)[n][c] / (sum_sp l_sp)[n,h] )
// ---------------------------------------------------------------------------
__global__ __launch_bounds__(256) void combine_kernel(
    const ushort* __restrict__ opart, const float* __restrict__ lpart,
    ushort* __restrict__ attnb)
{
    const int idx = blockIdx.x * 256 + threadIdx.x;   // one per 4 elements
    const int n   = idx >> 8;
    const int rem = idx & 255;
    const int h   = rem >> 4;
    const size_t e = (size_t)n * DIM + h * DH + (rem & 15) * 4;

    float s0 = 0.f, s1 = 0.f, s2 = 0.f, s3 = 0.f, lsum = 0.f;
    #pragma unroll
    for (int sp = 0; sp < NSPLIT; sp++) {
        ushort4 u = *(const ushort4*)&opart[(size_t)sp * N_CTX * DIM + e];
        s0 += bf2f(u.x); s1 += bf2f(u.y); s2 += bf2f(u.z); s3 += bf2f(u.w);
        lsum += lpart[(size_t)sp * NH * N_CTX + (size_t)h * N_CTX + n];
    }
    float li = 1.0f / lsum;

    ushort4 r;
    r.x = f2bf(s0 * li); r.y = f2bf(s1 * li);
    r.z = f2bf(s2 * li); r.w = f2bf(s3 * li);
    *(ushort4*)&attnb[e] = r;
}

// ---------------------------------------------------------------------------
// proj (MFMA): out[n][o] = sum_c A[n][c] * W[o][c] + b[o]
// 128x128 block tile (m93-class): 2:1 MFMA:ds_read, acc[4][4]/wave.
// Grid (32,8) = 256 blocks = exactly 1/CU, no tail.  (R8-verified.)
// ---------------------------------------------------------------------------
__global__ __launch_bounds__(256) void proj_kernel(
    const ushort* __restrict__ A, const ushort* __restrict__ W,
    const float* __restrict__ bias, float* __restrict__ out)
{
    __shared__ ushort As[128][72];
    __shared__ ushort Ws[128][72];

    const int nbase = blockIdx.x * 128;
    const int obase = blockIdx.y * 128;
    const int t    = threadIdx.x;
    const int w    = t >> 6;
    const int lane = t & 63;
    const int l15  = lane & 15;
    const int quad = lane >> 4;
    const int rw   = (w >> 1) * 64;
    const int cw   = (w & 1) * 64;

    f32x4 acc[4][4];
    #pragma unroll
    for (int mt = 0; mt < 4; mt++)
        #pragma unroll
        for (int nt = 0; nt < 4; nt++)
            acc[mt][nt] = (f32x4){0.f, 0.f, 0.f, 0.f};

    // staging: 4 x 16B chunks each of A and W; rows srow + i*32, i<4
    const int srow = t >> 3;
    const int scol = (t & 7) * 8;
    const ushort* apt = &A[(size_t)(nbase + srow) * DIM + scol];
    const ushort* wpt = &W[(size_t)(obase + srow) * DIM + scol];

    bf16x8 ar[4], wr[4];
    #pragma unroll
    for (int i = 0; i < 4; i++) {
        ar[i] = *(const bf16x8*)(apt + (size_t)i * 32 * DIM);
        wr[i] = *(const bf16x8*)(wpt + (size_t)i * 32 * DIM);
    }

    for (int kt = 0; kt < DIM / 64; kt++) {
        __syncthreads();                       // A: prev tile fully consumed
        #pragma unroll
        for (int i = 0; i < 4; i++) {
            *(bf16x8*)&As[srow + i * 32][scol] = ar[i];
            *(bf16x8*)&Ws[srow + i * 32][scol] = wr[i];
        }
        __syncthreads();                       // B: staging visible
        if (kt + 1 < DIM / 64) {               // prefetch next K-slab
            #pragma unroll
            for (int i = 0; i < 4; i++) {
                ar[i] = *(const bf16x8*)(apt + (size_t)(kt + 1) * 64 + (size_t)i * 32 * DIM);
                wr[i] = *(const bf16x8*)(wpt + (size_t)(kt + 1) * 64 + (size_t)i * 32 * DIM);
            }
        }

        bf16x8 af[4][2], bfr[4][2];
        #pragma unroll
        for (int mt = 0; mt < 4; mt++)
            #pragma unroll
            for (int kh = 0; kh < 2; kh++)
                af[mt][kh] = *(const bf16x8*)&As[rw + mt * 16 + l15][kh * 32 + quad * 8];
        #pragma unroll
        for (int nt = 0; nt < 4; nt++)
            #pragma unroll
            for (int kh = 0; kh < 2; kh++)
                bfr[nt][kh] = *(const bf16x8*)&Ws[cw + nt * 16 + l15][kh * 32 + quad * 8];

        #pragma unroll
        for (int mt = 0; mt < 4; mt++)
            #pragma unroll
            for (int nt = 0; nt < 4; nt++) {
                acc[mt][nt] = __builtin_amdgcn_mfma_f32_16x16x32_bf16(af[mt][0], bfr[nt][0], acc[mt][nt], 0, 0, 0);
                acc[mt][nt] = __builtin_amdgcn_mfma_f32_16x16x32_bf16(af[mt][1], bfr[nt][1], acc[mt][nt], 0, 0, 0);
            }
    }

    #pragma unroll
    for (int nt = 0; nt < 4; nt++) {
        int o = obase + cw + nt * 16 + l15;
        float bb = bias[o];
        #pragma unroll
        for (int mt = 0; mt < 4; mt++) {
            int nrow = nbase + rw + mt * 16 + quad * 4;
            out[(size_t)(nrow + 0) * DIM + o] = acc[mt][nt].x + bb;
            out[(size_t)(nrow + 1) * DIM + o] = acc[mt][nt].y + bb;
            out[(size_t)(nrow + 2) * DIM + o] = acc[mt][nt].z + bb;
            out[(size_t)(nrow + 3) * DIM + o] = acc[mt][nt].w + bb;
        }
    }
}

// ---------------------------------------------------------------------------
extern "C" void kernel_launch(void* const* d_in, const int* in_sizes, int n_in,
                              void* d_out, int out_size, void* d_ws, size_t ws_size,
                              hipStream_t stream)
{
    const float* q        = (const float*)d_in[0];
    const float* k        = (const float*)d_in[1];
    const float* v        = (const float*)d_in[2];
    const float* qk_scale = (const float*)d_in[3];
    const float* w_out    = (const float*)d_in[4];
    const float* b_out    = (const float*)d_in[5];
    float* out = (float*)d_out;

    const size_t per = (size_t)NH * N_CTX * DH;      // 4.19M elements
    ushort* qb    = (ushort*)d_ws;
    ushort* kb    = qb + per;
    ushort* vtg   = kb + per;
    ushort* attnb = vtg + per;                       // (N, DIM) bf16
    ushort* wb    = attnb + per;                     // (DIM, DIM) bf16
    ushort* opart = wb + (size_t)DIM * DIM;          // NSPLIT x (N, DIM) bf16
    float*  lpart = (float*)(opart + (size_t)NSPLIT * N_CTX * DIM);

    // 4 launches (was 7): front = prep-q | prep-k | vtrans | wconv fused.
    front_kernel<<<dim3(34816), 256, 0, stream>>>(q, k, v, w_out, qk_scale,
                                                  qb, kb, vtg, wb);
    attn_kernel<<<dim3(N_CTX / 256, NH, NSPLIT), 256, 0, stream>>>(qb, kb, vtg, opart, lpart);
    combine_kernel<<<dim3(N_CTX * DIM / 4 / 256), 256, 0, stream>>>(opart, lpart, attnb);
    proj_kernel<<<dim3(N_CTX / 128, DIM / 128), 256, 0, stream>>>(attnb, wb, b_out, out);
}